// Round 15
// baseline (100.623 us; speedup 1.0000x reference)
//
#include <hip/hip_runtime.h>

// DeformableConv2D round 19: r16 structure, PW=7 -> grid 1792 = 7.0 blocks/CU.
//
// r18 post-mortem: A'-in-registers regressed (88.2 vs 85.5) -- the per-tap
// serial VALU chain (s_off->clamp->floor->coords, x4 redundant) at the head of
// each tap's dataflow scheduled worse than the 120cy table read. Reverted.
//
// r16 pipe audit: VALU 24%, LDS ~29%, MFMA 2%, HBM 2% -- nothing saturated;
// main is latency + residency-quantization bound. Grid 896 = 3.5 blocks/CU
// (half-integer waste) and VGPR=68 caps residency at 4 blocks/CU; measured
// occupancy 23.6% = CUs average <2 live blocks. This round: PW=7, 1792 blocks
// = 7.0/CU integral work, ~2x independent blocks per slot, tail 1/3.5 -> 1/7.
// Cost: phase A's per-block fixed cost (18 MFMA + 18 b128/wave, LDS-fed)
// amortizes over 7 px (+~1.8us pipe work). LDS 31.7 -> 17.1 KB.
// All math r16 verbatim (phase A window-fed, tabled A', branchless phase B).
//
// LDS: s_winh 7040 + s_off 2016 + s_cww 4608 + s_cwl 2304 + s_cwf 1152
//    = 17120 B. Barriers per block: 3.
//
// MFMA 16x16x32 f16 layouts (verified by earlier passing runs):
//   A-frag: lane holds A[m=lane&15][k=(lane>>4)*8+j]
//   B-frag: lane holds B[k=(lane>>4)*8+j][n=lane&15]   (B stored [n][k])
//   C/D  : col(n)=lane&15, row(m)=(lane>>4)*4+reg

#define NH 56
#define NW 56
#define NC 64
#define NDG 4
#define NK 9
#define NOFF 72
#define NOFFP 80
#define NF 64
#define KTOT 576
#define HWPIX 3136
#define NPIX 12544

#define PW    7             // pixels per block (one row segment; 8 segs/row)
#define WR    5             // window rows  (oh-2 .. oh+2)
#define WC    11            // window cols  (ow0-2 .. ow0+8)
#define WPOS  (WR * WC)     // 55 positions
#define NBLK  (4 * NH * 8)  // 1792 = 7.0 blocks/CU

#define WS_OFFKT 0          // f16 [80][576]   = 92160 B
#define WS_WK    92160      // f16 [9][64][64] = 73728 B

typedef _Float16 half8   __attribute__((ext_vector_type(8)));
typedef _Float16 half4   __attribute__((ext_vector_type(4)));
typedef float    floatx4 __attribute__((ext_vector_type(4)));

// ---------------- prep: weight conversion ----------------
__global__ __launch_bounds__(256)
void dcn_prep(const float* __restrict__ offk,   // [3,3,64,72] (kk,oc)
              const float* __restrict__ wk,     // [3,3,64,64] (k,f,c)
              _Float16* __restrict__ offkt,     // [80][576]   (oc,kk)
              _Float16* __restrict__ wkh)       // [9][64][64]
{
    const int i = blockIdx.x * 256 + threadIdx.x;
    if (i < NOFFP * KTOT) {
        const int oc = i / KTOT;
        const int kk = i - oc * KTOT;
        const float v = (oc < NOFF) ? offk[kk * NOFF + oc] : 0.0f;
        offkt[i] = (_Float16)v;
    }
    const int j = i - NOFFP * KTOT;
    if (j >= 0 && j < NK * NF * NC) wkh[j] = (_Float16)wk[j];
}

// f16 window swizzle (16B granules contiguous; spread banks across pos)
__device__ __forceinline__ int winh_idx(int pos, int c) {     // elem units
    return (pos << 6) + (c ^ ((pos & 7) << 3));
}

// ---------------- fused main ----------------
__global__ __launch_bounds__(256, 4)
void dcn_main(const float* __restrict__ x,        // [4,56,56,64]
              const _Float16* __restrict__ offkt, // [80][576]
              const float* __restrict__ offb,     // [72]
              const _Float16* __restrict__ wkh,   // [9][64][64]
              float* __restrict__ out)            // [12544][64]
{
    __shared__ __align__(16) _Float16 s_winh[WPOS * NC];    // 7040 B
    __shared__ float s_off[PW * NOFF];                      // 2016 B
    __shared__ __align__(16) float s_cww[36 * 8 * 4];       // 4608 B  [k*4+g][p]
    __shared__ __align__(8)  unsigned s_cwl[36 * 8 * 2];    // 2304 B  [k*4+g][p]
    __shared__ unsigned s_cwf[36 * 8];                      // 1152 B  fallback

    const int tid  = threadIdx.x;
    const int w    = tid >> 6;      // wave id: A = N-tile, B = group
    const int lane = tid & 63;
    const int m    = lane & 15;     // MFMA row / col index
    const int kq   = lane >> 4;     // MFMA k-quad
    const int kq8  = kq * 8;

    // block -> (b, oh, ow0)
    const int blk = blockIdx.x;
    const int b   = blk / (NH * 8);
    const int r2  = blk - b * (NH * 8);
    const int oh  = r2 >> 3;
    const int ow0 = (r2 & 7) * PW;
    const int bb  = b * HWPIX;

    // ---- stage window (f16), zero-padded outside image ----
    for (int i = tid; i < WPOS * 16; i += 256) {
        const int pos = i >> 4;
        const int g4  = (i & 15) * 4;
        const int ry  = pos / WC;
        const int rx  = pos - ry * WC;
        const int iy  = oh + ry - 2;
        const int ix  = ow0 + rx - 2;
        float4 v = make_float4(0.f, 0.f, 0.f, 0.f);
        if ((unsigned)iy < NH && (unsigned)ix < NW)
            v = *(const float4*)&x[(size_t)((bb + iy * NW + ix) * NC) + g4];
        half4 h;
        h[0] = (_Float16)v.x; h[1] = (_Float16)v.y;
        h[2] = (_Float16)v.z; h[3] = (_Float16)v.w;
        *(half4*)&s_winh[winh_idx(pos, g4)] = h;
    }
    __syncthreads();

    // ---- phase A: offset conv GEMM from f16 window (r16 verbatim) ----
    const int oc0 = w * 16 + m;     // 0..63
    floatx4 acc0, acc1;
    { const float bv = offb[oc0]; acc0 = (floatx4){bv, bv, bv, bv}; }
    { const float bv = (w == 3 && m < 8) ? offb[64 + m] : 0.0f;
      acc1 = (floatx4){bv, bv, bv, bv}; }

    #pragma unroll
    for (int k = 0; k < NK; ++k) {
        const int ki = k / 3, kj = k - 3 * ki;
        // m>=PW rows read garbage in-window positions (pos<=51<55); masked.
        const int pos = (ki + 1) * WC + (m + kj + 1);
        #pragma unroll
        for (int s = 0; s < 2; ++s) {
            const half8 af = *(const half8*)&s_winh[winh_idx(pos, s * 32 + kq8)];
            const int kkb = k * 64 + s * 32 + kq8;
            const half8 bf0 = *(const half8*)&offkt[(size_t)oc0 * KTOT + kkb];
            acc0 = __builtin_amdgcn_mfma_f32_16x16x32_f16(af, bf0, acc0, 0, 0, 0);
            if (w == 3) {
                const half8 bf1 = *(const half8*)&offkt[(size_t)(64 + m) * KTOT + kkb];
                acc1 = __builtin_amdgcn_mfma_f32_16x16x32_f16(af, bf1, acc1, 0, 0, 0);
            }
        }
    }
    #pragma unroll
    for (int r = 0; r < 4; ++r)
        if (kq * 4 + r < PW)
            s_off[(kq * 4 + r) * NOFF + oc0] = acc0[r];
    if (w == 3 && m < 8) {
        #pragma unroll
        for (int r = 0; r < 4; ++r)
            if (kq * 4 + r < PW)
                s_off[(kq * 4 + r) * NOFF + 64 + m] = acc1[r];
    }
    __syncthreads();

    // ---- phase A': coord/weight table, slot = (k*4+g)*8 + p ----
    for (int i = tid; i < 36 * 8; i += 256) {
        const int kg = i >> 3;                  // k*NDG + g
        const int p  = i & 7;
        float4 wv = make_float4(0.f, 0.f, 0.f, 0.f);
        unsigned c0 = 0, c1 = 0, cfv = 0;       // pad slots: pos 0, weight 0
        if (p < PW) {
            const int k  = kg >> 2;
            const int ki = k / 3, kj = k - 3 * ki;
            const int ow = ow0 + p;
            const float offy = s_off[p * NOFF + kg * 2 + 0];
            const float offx = s_off[p * NOFF + kg * 2 + 1];
            float yv = fminf(fmaxf((float)(oh + ki) + offy, 0.0f), 57.0f);
            float xv = fminf(fmaxf((float)(ow + kj) + offx, 0.0f), 57.0f);
            const float y0f = floorf(yv), x0f = floorf(xv);
            const int y0 = (int)y0f, x0 = (int)x0f;
            const int y1 = min(y0 + 1, 57), x1 = min(x0 + 1, 57);
            const float ly = yv - y0f,       lx = xv - x0f;
            const float hy = (float)y1 - yv, hx = (float)x1 - xv;
            const bool vy0 = (unsigned)(y0 - 1) < NH;
            const bool vy1 = (unsigned)(y1 - 1) < NH;
            const bool vx0 = (unsigned)(x0 - 1) < NW;
            const bool vx1 = (unsigned)(x1 - 1) < NW;
            wv = make_float4((vy0 && vx0) ? hy * hx : 0.0f,
                             (vy0 && vx1) ? hy * lx : 0.0f,
                             (vy1 && vx0) ? ly * hx : 0.0f,
                             (vy1 && vx1) ? ly * lx : 0.0f);
            const int y0c = min(max(y0 - 1, 0), NH - 1);
            const int y1c = min(max(y1 - 1, 0), NH - 1);
            const int x0c = min(max(x0 - 1, 0), NW - 1);
            const int x1c = min(max(x1 - 1, 0), NW - 1);
            const int ry0 = y0c - oh + 2, ry1 = y1c - oh + 2;
            const int rx0 = x0c - ow0 + 2, rx1 = x1c - ow0 + 2;
            if ((unsigned)ry0 < WR && (unsigned)ry1 < WR &&
                (unsigned)rx0 < WC && (unsigned)rx1 < WC) {
                c0 = (unsigned)(ry0 * WC + rx0) | ((unsigned)(ry0 * WC + rx1) << 16);
                c1 = (unsigned)(ry1 * WC + rx0) | ((unsigned)(ry1 * WC + rx1) << 16);
            } else {                            // rare: coords to s_cwf; pos 0
                cfv = 0x80000000u | ((unsigned)y0c << 18) | ((unsigned)x0c << 12)
                    | ((unsigned)y1c << 6) | (unsigned)x1c;
            }
        }
        *(float4*)&s_cww[i * 4] = wv;
        s_cwl[i * 2 + 0] = c0;
        s_cwl[i * 2 + 1] = c1;
        s_cwf[i] = cfv;
    }
    __syncthreads();

    // ---- phase B: branchless window path, full unroll, rare fixup ----
    floatx4 accB = (floatx4){0.f, 0.f, 0.f, 0.f};
    const int p  = (m < PW) ? m : PW - 1;       // m>=PW lanes: clamped, masked
    const int tb = w * 8 + p;                   // table slot (pixel p, group w)
    #pragma unroll
    for (int k = 0; k < NK; ++k) {
        const int sl = k * 32 + tb;
        const float4   cw = *(const float4*)&s_cww[sl * 4];
        const unsigned c0 = s_cwl[sl * 2 + 0];
        const unsigned c1 = s_cwl[sl * 2 + 1];
        const unsigned cf = s_cwf[sl];

        const _Float16* wp = &wkh[(size_t)(k * NF + w * 16 + m) * NC];
        const half8 bf0 = *(const half8*)&wp[kq8];
        const half8 bf1 = *(const half8*)&wp[32 + kq8];

        // always-on window reads (fallback slots read pos 0: benign)
        const int p00 = c0 & 0xFFFF, p01 = c0 >> 16;
        const int p10 = c1 & 0xFFFF, p11 = c1 >> 16;
        const int ca = kq8, cb = 32 + kq8;
        const half8 q00a = *(const half8*)&s_winh[winh_idx(p00, ca)];
        const half8 q01a = *(const half8*)&s_winh[winh_idx(p01, ca)];
        const half8 q10a = *(const half8*)&s_winh[winh_idx(p10, ca)];
        const half8 q11a = *(const half8*)&s_winh[winh_idx(p11, ca)];
        const half8 q00b = *(const half8*)&s_winh[winh_idx(p00, cb)];
        const half8 q01b = *(const half8*)&s_winh[winh_idx(p01, cb)];
        const half8 q10b = *(const half8*)&s_winh[winh_idx(p10, cb)];
        const half8 q11b = *(const half8*)&s_winh[winh_idx(p11, cb)];

        half8 af0, af1;
        #pragma unroll
        for (int j = 0; j < 8; ++j) {
            float v0 = cw.x * (float)q00a[j];       // v_fma_mix_f32 chain
            v0 = fmaf(cw.y, (float)q01a[j], v0);
            v0 = fmaf(cw.z, (float)q10a[j], v0);
            v0 = fmaf(cw.w, (float)q11a[j], v0);
            af0[j] = (_Float16)v0;
            float v1 = cw.x * (float)q00b[j];
            v1 = fmaf(cw.y, (float)q01b[j], v1);
            v1 = fmaf(cw.z, (float)q10b[j], v1);
            v1 = fmaf(cw.w, (float)q11b[j], v1);
            af1[j] = (_Float16)v1;
        }

        if (__builtin_expect(cf != 0, 0)) {     // rare fixup: overwrite af
            const int y0c = (cf >> 18) & 63, x0c = (cf >> 12) & 63;
            const int y1c = (cf >> 6) & 63,  x1c = cf & 63;
            const int i00 = (bb + y0c * NW + x0c) * NC;
            const int i01 = (bb + y0c * NW + x1c) * NC;
            const int i10 = (bb + y1c * NW + x0c) * NC;
            const int i11 = (bb + y1c * NW + x1c) * NC;
            #pragma unroll
            for (int j = 0; j < 8; ++j) {
                float v0 = cw.x * (float)(_Float16)x[i00 + kq8 + j];
                v0 = fmaf(cw.y, (float)(_Float16)x[i01 + kq8 + j], v0);
                v0 = fmaf(cw.z, (float)(_Float16)x[i10 + kq8 + j], v0);
                v0 = fmaf(cw.w, (float)(_Float16)x[i11 + kq8 + j], v0);
                af0[j] = (_Float16)v0;
                float v1 = cw.x * (float)(_Float16)x[i00 + 32 + kq8 + j];
                v1 = fmaf(cw.y, (float)(_Float16)x[i01 + 32 + kq8 + j], v1);
                v1 = fmaf(cw.z, (float)(_Float16)x[i10 + 32 + kq8 + j], v1);
                v1 = fmaf(cw.w, (float)(_Float16)x[i11 + 32 + kq8 + j], v1);
                af1[j] = (_Float16)v1;
            }
        }

        accB = __builtin_amdgcn_mfma_f32_16x16x32_f16(af0, bf0, accB, 0, 0, 0);
        accB = __builtin_amdgcn_mfma_f32_16x16x32_f16(af1, bf1, accB, 0, 0, 0);
    }

    #pragma unroll
    for (int r = 0; r < 4; ++r) {
        const int row = kq * 4 + r;
        if (row < PW)
            out[(size_t)(bb + oh * NW + ow0 + row) * NF + w * 16 + m] = accB[r];
    }
}

extern "C" void kernel_launch(void* const* d_in, const int* in_sizes, int n_in,
                              void* d_out, int out_size, void* d_ws, size_t ws_size,
                              hipStream_t stream) {
    const float* xin  = (const float*)d_in[0];
    const float* offk = (const float*)d_in[1];
    const float* offb = (const float*)d_in[2];
    const float* wk   = (const float*)d_in[3];
    float* outp = (float*)d_out;

    _Float16* offkt = (_Float16*)((char*)d_ws + WS_OFFKT);
    _Float16* wkh   = (_Float16*)((char*)d_ws + WS_WK);

    dcn_prep<<<324, 256, 0, stream>>>(offk, wk, offkt, wkh);
    dcn_main<<<NBLK, 256, 0, stream>>>(xin, offkt, offb, wkh, outp);
}

// Round 16
// 84.993 us; speedup vs baseline: 1.1839x; 1.1839x over previous
//
#include <hip/hip_runtime.h>

// DeformableConv2D round 20: r16 structure, 2x8 pixel tile (16 px, FULL MFMA M).
//
// r19 post-mortem: PW=7 doubled main (29->65us) -- phase-B cost is per-BLOCK
// fixed (9 taps x 8 corner reads x 4 waves, all 16 M-rows computed regardless
// of PW), so cost scales with block count, and occupancy (23->34%) was never
// the binding constraint. Corrected model: main ~ #blocks; r16 wastes 2/16
// M-rows.
//
// This round: block = 2-row x 8-col pixel tile -> all 16 M-rows are real
// pixels. Grid 896 -> 784 (-12.5% of every per-block cost); window 90 -> 72
// positions (6 rows x 12 cols, -20% staging); all row<PW masks deleted.
// Pixel of M-row m: (oh + (m>>3), ow0 + (m&7)).
// Per-tap math / blend / tables / fallback are r16 VERBATIM -> absmax
// unchanged (0.015625 expected).
//
// LDS: s_winh 9216 + s_off 4608 + s_cww 9216 + s_cwl 4608 + s_cwf 2304
//    = 29952 B. Barriers per block: 3.
//
// MFMA 16x16x32 f16 layouts (verified by earlier passing runs):
//   A-frag: lane holds A[m=lane&15][k=(lane>>4)*8+j]
//   B-frag: lane holds B[k=(lane>>4)*8+j][n=lane&15]   (B stored [n][k])
//   C/D  : col(n)=lane&15, row(m)=(lane>>4)*4+reg

#define NH 56
#define NW 56
#define NC 64
#define NDG 4
#define NK 9
#define NOFF 72
#define NOFFP 80
#define NF 64
#define KTOT 576
#define HWPIX 3136
#define NPIX 12544

#define PR    2             // pixel tile rows
#define PC    8             // pixel tile cols
#define WR    6             // window rows  (oh-2 .. oh+3)
#define WC    12            // window cols  (ow0-2 .. ow0+9)
#define WPOS  (WR * WC)     // 72 positions
#define NBLK  (4 * (NH / PR) * (NW / PC))   // 4*28*7 = 784

#define WS_OFFKT 0          // f16 [80][576]   = 92160 B
#define WS_WK    92160      // f16 [9][64][64] = 73728 B

typedef _Float16 half8   __attribute__((ext_vector_type(8)));
typedef _Float16 half4   __attribute__((ext_vector_type(4)));
typedef float    floatx4 __attribute__((ext_vector_type(4)));

// ---------------- prep: weight conversion ----------------
__global__ __launch_bounds__(256)
void dcn_prep(const float* __restrict__ offk,   // [3,3,64,72] (kk,oc)
              const float* __restrict__ wk,     // [3,3,64,64] (k,f,c)
              _Float16* __restrict__ offkt,     // [80][576]   (oc,kk)
              _Float16* __restrict__ wkh)       // [9][64][64]
{
    const int i = blockIdx.x * 256 + threadIdx.x;
    if (i < NOFFP * KTOT) {
        const int oc = i / KTOT;
        const int kk = i - oc * KTOT;
        const float v = (oc < NOFF) ? offk[kk * NOFF + oc] : 0.0f;
        offkt[i] = (_Float16)v;
    }
    const int j = i - NOFFP * KTOT;
    if (j >= 0 && j < NK * NF * NC) wkh[j] = (_Float16)wk[j];
}

// f16 window swizzle (16B granules contiguous; spread banks across pos)
__device__ __forceinline__ int winh_idx(int pos, int c) {     // elem units
    return (pos << 6) + (c ^ ((pos & 7) << 3));
}

// ---------------- fused main ----------------
__global__ __launch_bounds__(256, 4)
void dcn_main(const float* __restrict__ x,        // [4,56,56,64]
              const _Float16* __restrict__ offkt, // [80][576]
              const float* __restrict__ offb,     // [72]
              const _Float16* __restrict__ wkh,   // [9][64][64]
              float* __restrict__ out)            // [12544][64]
{
    __shared__ __align__(16) _Float16 s_winh[WPOS * NC];    // 9216 B
    __shared__ float s_off[16 * NOFF];                      // 4608 B
    __shared__ __align__(16) float s_cww[36 * 16 * 4];      // 9216 B  [k*4+g][p]
    __shared__ __align__(8)  unsigned s_cwl[36 * 16 * 2];   // 4608 B  [k*4+g][p]
    __shared__ unsigned s_cwf[36 * 16];                     // 2304 B  fallback

    const int tid  = threadIdx.x;
    const int w    = tid >> 6;      // wave id: A = N-tile, B = group
    const int lane = tid & 63;
    const int m    = lane & 15;     // MFMA row / col index
    const int kq   = lane >> 4;     // MFMA k-quad
    const int kq8  = kq * 8;

    // block -> (b, oh, ow0): 2-row x 8-col pixel tile
    const int blk = blockIdx.x;
    const int b   = blk / ((NH / PR) * (NW / PC));          // /196
    const int r2  = blk - b * ((NH / PR) * (NW / PC));
    const int oh  = (r2 / (NW / PC)) * PR;                  // 0,2,..,54
    const int ow0 = (r2 - (r2 / (NW / PC)) * (NW / PC)) * PC;
    const int bb  = b * HWPIX;

    // ---- stage window (f16), zero-padded outside image ----
    for (int i = tid; i < WPOS * 16; i += 256) {
        const int pos = i >> 4;
        const int g4  = (i & 15) * 4;
        const int ry  = pos / WC;
        const int rx  = pos - ry * WC;
        const int iy  = oh + ry - 2;
        const int ix  = ow0 + rx - 2;
        float4 v = make_float4(0.f, 0.f, 0.f, 0.f);
        if ((unsigned)iy < NH && (unsigned)ix < NW)
            v = *(const float4*)&x[(size_t)((bb + iy * NW + ix) * NC) + g4];
        half4 h;
        h[0] = (_Float16)v.x; h[1] = (_Float16)v.y;
        h[2] = (_Float16)v.z; h[3] = (_Float16)v.w;
        *(half4*)&s_winh[winh_idx(pos, g4)] = h;
    }
    __syncthreads();

    // ---- phase A: offset conv GEMM from f16 window (all 16 rows real) ----
    const int oc0 = w * 16 + m;     // 0..63
    floatx4 acc0, acc1;
    { const float bv = offb[oc0]; acc0 = (floatx4){bv, bv, bv, bv}; }
    { const float bv = (w == 3 && m < 8) ? offb[64 + m] : 0.0f;
      acc1 = (floatx4){bv, bv, bv, bv}; }

    #pragma unroll
    for (int k = 0; k < NK; ++k) {
        const int ki = k / 3, kj = k - 3 * ki;
        // pixel of row m: (oh + (m>>3), ow0 + (m&7)); window-relative:
        const int pos = (ki + 1 + (m >> 3)) * WC + ((m & 7) + kj + 1);
        #pragma unroll
        for (int s = 0; s < 2; ++s) {
            const half8 af = *(const half8*)&s_winh[winh_idx(pos, s * 32 + kq8)];
            const int kkb = k * 64 + s * 32 + kq8;
            const half8 bf0 = *(const half8*)&offkt[(size_t)oc0 * KTOT + kkb];
            acc0 = __builtin_amdgcn_mfma_f32_16x16x32_f16(af, bf0, acc0, 0, 0, 0);
            if (w == 3) {
                const half8 bf1 = *(const half8*)&offkt[(size_t)(64 + m) * KTOT + kkb];
                acc1 = __builtin_amdgcn_mfma_f32_16x16x32_f16(af, bf1, acc1, 0, 0, 0);
            }
        }
    }
    #pragma unroll
    for (int r = 0; r < 4; ++r)
        s_off[(kq * 4 + r) * NOFF + oc0] = acc0[r];
    if (w == 3 && m < 8) {
        #pragma unroll
        for (int r = 0; r < 4; ++r)
            s_off[(kq * 4 + r) * NOFF + 64 + m] = acc1[r];
    }
    __syncthreads();

    // ---- phase A': coord/weight table, slot = (k*4+g)*16 + p ----
    for (int i = tid; i < 36 * 16; i += 256) {
        const int kg = i >> 4;                  // k*NDG + g
        const int p  = i & 15;                  // pixel 0..15 (all real)
        const int k  = kg >> 2;
        const int ki = k / 3, kj = k - 3 * ki;
        const int ohp = oh + (p >> 3);
        const int owp = ow0 + (p & 7);
        const float offy = s_off[p * NOFF + kg * 2 + 0];
        const float offx = s_off[p * NOFF + kg * 2 + 1];
        float yv = fminf(fmaxf((float)(ohp + ki) + offy, 0.0f), 57.0f);
        float xv = fminf(fmaxf((float)(owp + kj) + offx, 0.0f), 57.0f);
        const float y0f = floorf(yv), x0f = floorf(xv);
        const int y0 = (int)y0f, x0 = (int)x0f;
        const int y1 = min(y0 + 1, 57), x1 = min(x0 + 1, 57);
        const float ly = yv - y0f,       lx = xv - x0f;
        const float hy = (float)y1 - yv, hx = (float)x1 - xv;
        const bool vy0 = (unsigned)(y0 - 1) < NH;
        const bool vy1 = (unsigned)(y1 - 1) < NH;
        const bool vx0 = (unsigned)(x0 - 1) < NW;
        const bool vx1 = (unsigned)(x1 - 1) < NW;
        const float4 wv = make_float4((vy0 && vx0) ? hy * hx : 0.0f,
                                      (vy0 && vx1) ? hy * lx : 0.0f,
                                      (vy1 && vx0) ? ly * hx : 0.0f,
                                      (vy1 && vx1) ? ly * lx : 0.0f);
        const int y0c = min(max(y0 - 1, 0), NH - 1);
        const int y1c = min(max(y1 - 1, 0), NH - 1);
        const int x0c = min(max(x0 - 1, 0), NW - 1);
        const int x1c = min(max(x1 - 1, 0), NW - 1);
        const int ry0 = y0c - oh + 2, ry1 = y1c - oh + 2;
        const int rx0 = x0c - ow0 + 2, rx1 = x1c - ow0 + 2;
        unsigned c0 = 0, c1 = 0, cfv = 0;
        if ((unsigned)ry0 < WR && (unsigned)ry1 < WR &&
            (unsigned)rx0 < WC && (unsigned)rx1 < WC) {
            c0 = (unsigned)(ry0 * WC + rx0) | ((unsigned)(ry0 * WC + rx1) << 16);
            c1 = (unsigned)(ry1 * WC + rx0) | ((unsigned)(ry1 * WC + rx1) << 16);
        } else {                                // rare: coords to s_cwf; pos 0
            cfv = 0x80000000u | ((unsigned)y0c << 18) | ((unsigned)x0c << 12)
                | ((unsigned)y1c << 6) | (unsigned)x1c;
        }
        *(float4*)&s_cww[i * 4] = wv;
        s_cwl[i * 2 + 0] = c0;
        s_cwl[i * 2 + 1] = c1;
        s_cwf[i] = cfv;
    }
    __syncthreads();

    // ---- phase B: branchless window path, full unroll, rare fixup ----
    floatx4 accB = (floatx4){0.f, 0.f, 0.f, 0.f};
    const int tb = w * 16 + m;                  // table slot (pixel m, group w)
    #pragma unroll
    for (int k = 0; k < NK; ++k) {
        const int sl = k * 64 + tb;
        const float4   cw = *(const float4*)&s_cww[sl * 4];
        const unsigned c0 = s_cwl[sl * 2 + 0];
        const unsigned c1 = s_cwl[sl * 2 + 1];
        const unsigned cf = s_cwf[sl];

        const _Float16* wp = &wkh[(size_t)(k * NF + w * 16 + m) * NC];
        const half8 bf0 = *(const half8*)&wp[kq8];
        const half8 bf1 = *(const half8*)&wp[32 + kq8];

        // always-on window reads (fallback slots read pos 0: benign)
        const int p00 = c0 & 0xFFFF, p01 = c0 >> 16;
        const int p10 = c1 & 0xFFFF, p11 = c1 >> 16;
        const int ca = kq8, cb = 32 + kq8;
        const half8 q00a = *(const half8*)&s_winh[winh_idx(p00, ca)];
        const half8 q01a = *(const half8*)&s_winh[winh_idx(p01, ca)];
        const half8 q10a = *(const half8*)&s_winh[winh_idx(p10, ca)];
        const half8 q11a = *(const half8*)&s_winh[winh_idx(p11, ca)];
        const half8 q00b = *(const half8*)&s_winh[winh_idx(p00, cb)];
        const half8 q01b = *(const half8*)&s_winh[winh_idx(p01, cb)];
        const half8 q10b = *(const half8*)&s_winh[winh_idx(p10, cb)];
        const half8 q11b = *(const half8*)&s_winh[winh_idx(p11, cb)];

        half8 af0, af1;
        #pragma unroll
        for (int j = 0; j < 8; ++j) {
            float v0 = cw.x * (float)q00a[j];       // v_fma_mix_f32 chain
            v0 = fmaf(cw.y, (float)q01a[j], v0);
            v0 = fmaf(cw.z, (float)q10a[j], v0);
            v0 = fmaf(cw.w, (float)q11a[j], v0);
            af0[j] = (_Float16)v0;
            float v1 = cw.x * (float)q00b[j];
            v1 = fmaf(cw.y, (float)q01b[j], v1);
            v1 = fmaf(cw.z, (float)q10b[j], v1);
            v1 = fmaf(cw.w, (float)q11b[j], v1);
            af1[j] = (_Float16)v1;
        }

        if (__builtin_expect(cf != 0, 0)) {     // rare fixup: overwrite af
            const int y0c = (cf >> 18) & 63, x0c = (cf >> 12) & 63;
            const int y1c = (cf >> 6) & 63,  x1c = cf & 63;
            const int i00 = (bb + y0c * NW + x0c) * NC;
            const int i01 = (bb + y0c * NW + x1c) * NC;
            const int i10 = (bb + y1c * NW + x0c) * NC;
            const int i11 = (bb + y1c * NW + x1c) * NC;
            #pragma unroll
            for (int j = 0; j < 8; ++j) {
                float v0 = cw.x * (float)(_Float16)x[i00 + kq8 + j];
                v0 = fmaf(cw.y, (float)(_Float16)x[i01 + kq8 + j], v0);
                v0 = fmaf(cw.z, (float)(_Float16)x[i10 + kq8 + j], v0);
                v0 = fmaf(cw.w, (float)(_Float16)x[i11 + kq8 + j], v0);
                af0[j] = (_Float16)v0;
                float v1 = cw.x * (float)(_Float16)x[i00 + 32 + kq8 + j];
                v1 = fmaf(cw.y, (float)(_Float16)x[i01 + 32 + kq8 + j], v1);
                v1 = fmaf(cw.z, (float)(_Float16)x[i10 + 32 + kq8 + j], v1);
                v1 = fmaf(cw.w, (float)(_Float16)x[i11 + 32 + kq8 + j], v1);
                af1[j] = (_Float16)v1;
            }
        }

        accB = __builtin_amdgcn_mfma_f32_16x16x32_f16(af0, bf0, accB, 0, 0, 0);
        accB = __builtin_amdgcn_mfma_f32_16x16x32_f16(af1, bf1, accB, 0, 0, 0);
    }

    #pragma unroll
    for (int r = 0; r < 4; ++r) {
        const int row = kq * 4 + r;             // all 16 rows are real pixels
        out[(size_t)(bb + (oh + (row >> 3)) * NW + ow0 + (row & 7)) * NF
            + w * 16 + m] = accB[r];
    }
}

extern "C" void kernel_launch(void* const* d_in, const int* in_sizes, int n_in,
                              void* d_out, int out_size, void* d_ws, size_t ws_size,
                              hipStream_t stream) {
    const float* xin  = (const float*)d_in[0];
    const float* offk = (const float*)d_in[1];
    const float* offb = (const float*)d_in[2];
    const float* wk   = (const float*)d_in[3];
    float* outp = (float*)d_out;

    _Float16* offkt = (_Float16*)((char*)d_ws + WS_OFFKT);
    _Float16* wkh   = (_Float16*)((char*)d_ws + WS_WK);

    dcn_prep<<<324, 256, 0, stream>>>(offk, wk, offkt, wkh);
    dcn_main<<<NBLK, 256, 0, stream>>>(xin, offkt, offb, wkh, outp);
}

// Round 17
// 83.408 us; speedup vs baseline: 1.2064x; 1.0190x over previous
//
#include <hip/hip_runtime.h>

// DeformableConv2D round 21: r20 base + PACKED-F16 BLEND (v_pk_fma_f16).
//
// r20 post-mortem: 2x8 tile won small (85.0 bench, main ~28.5us) but -12.5%
// block count bought only -2% -- main is latency-floor dominated (one block's
// chain lifetime), not additive pipe work. The one pipe INSIDE the per-tap
// dependency chain not yet shrunk: the blend (64 v_fma_mix + 16 cvt per lane
// per tap between LDS corner reads and MFMA).
//
// This round: weights cvt to f16 once per tap; blend as whole-half8
// elementwise ops -> v_pk_fma_f16 (2 elem/op): 80 VALU ops/tap -> 32, and the
// f32->f16 cvt chain disappears (af stays f16 end-to-end).
// Numerics: blend accumulates in f16 (sample err ~2x, est absmax 0.02-0.035
// vs thr 0.069; current 0.0156). Fallback path keeps f32 math (rare).
// Everything else r20 verbatim.
//
// LDS: s_winh 9216 + s_off 4608 + s_cww 9216 + s_cwl 4608 + s_cwf 2304
//    = 29952 B. Barriers per block: 3.
//
// MFMA 16x16x32 f16 layouts (verified by earlier passing runs):
//   A-frag: lane holds A[m=lane&15][k=(lane>>4)*8+j]
//   B-frag: lane holds B[k=(lane>>4)*8+j][n=lane&15]   (B stored [n][k])
//   C/D  : col(n)=lane&15, row(m)=(lane>>4)*4+reg

#define NH 56
#define NW 56
#define NC 64
#define NDG 4
#define NK 9
#define NOFF 72
#define NOFFP 80
#define NF 64
#define KTOT 576
#define HWPIX 3136
#define NPIX 12544

#define PR    2             // pixel tile rows
#define PC    8             // pixel tile cols
#define WR    6             // window rows  (oh-2 .. oh+3)
#define WC    12            // window cols  (ow0-2 .. ow0+9)
#define WPOS  (WR * WC)     // 72 positions
#define NBLK  (4 * (NH / PR) * (NW / PC))   // 4*28*7 = 784

#define WS_OFFKT 0          // f16 [80][576]   = 92160 B
#define WS_WK    92160      // f16 [9][64][64] = 73728 B

typedef _Float16 half8   __attribute__((ext_vector_type(8)));
typedef _Float16 half4   __attribute__((ext_vector_type(4)));
typedef float    floatx4 __attribute__((ext_vector_type(4)));

// ---------------- prep: weight conversion ----------------
__global__ __launch_bounds__(256)
void dcn_prep(const float* __restrict__ offk,   // [3,3,64,72] (kk,oc)
              const float* __restrict__ wk,     // [3,3,64,64] (k,f,c)
              _Float16* __restrict__ offkt,     // [80][576]   (oc,kk)
              _Float16* __restrict__ wkh)       // [9][64][64]
{
    const int i = blockIdx.x * 256 + threadIdx.x;
    if (i < NOFFP * KTOT) {
        const int oc = i / KTOT;
        const int kk = i - oc * KTOT;
        const float v = (oc < NOFF) ? offk[kk * NOFF + oc] : 0.0f;
        offkt[i] = (_Float16)v;
    }
    const int j = i - NOFFP * KTOT;
    if (j >= 0 && j < NK * NF * NC) wkh[j] = (_Float16)wk[j];
}

// f16 window swizzle (16B granules contiguous; spread banks across pos)
__device__ __forceinline__ int winh_idx(int pos, int c) {     // elem units
    return (pos << 6) + (c ^ ((pos & 7) << 3));
}

// ---------------- fused main ----------------
__global__ __launch_bounds__(256, 4)
void dcn_main(const float* __restrict__ x,        // [4,56,56,64]
              const _Float16* __restrict__ offkt, // [80][576]
              const float* __restrict__ offb,     // [72]
              const _Float16* __restrict__ wkh,   // [9][64][64]
              float* __restrict__ out)            // [12544][64]
{
    __shared__ __align__(16) _Float16 s_winh[WPOS * NC];    // 9216 B
    __shared__ float s_off[16 * NOFF];                      // 4608 B
    __shared__ __align__(16) float s_cww[36 * 16 * 4];      // 9216 B  [k*4+g][p]
    __shared__ __align__(8)  unsigned s_cwl[36 * 16 * 2];   // 4608 B  [k*4+g][p]
    __shared__ unsigned s_cwf[36 * 16];                     // 2304 B  fallback

    const int tid  = threadIdx.x;
    const int w    = tid >> 6;      // wave id: A = N-tile, B = group
    const int lane = tid & 63;
    const int m    = lane & 15;     // MFMA row / col index
    const int kq   = lane >> 4;     // MFMA k-quad
    const int kq8  = kq * 8;

    // block -> (b, oh, ow0): 2-row x 8-col pixel tile
    const int blk = blockIdx.x;
    const int b   = blk / ((NH / PR) * (NW / PC));          // /196
    const int r2  = blk - b * ((NH / PR) * (NW / PC));
    const int oh  = (r2 / (NW / PC)) * PR;                  // 0,2,..,54
    const int ow0 = (r2 - (r2 / (NW / PC)) * (NW / PC)) * PC;
    const int bb  = b * HWPIX;

    // ---- stage window (f16), zero-padded outside image ----
    for (int i = tid; i < WPOS * 16; i += 256) {
        const int pos = i >> 4;
        const int g4  = (i & 15) * 4;
        const int ry  = pos / WC;
        const int rx  = pos - ry * WC;
        const int iy  = oh + ry - 2;
        const int ix  = ow0 + rx - 2;
        float4 v = make_float4(0.f, 0.f, 0.f, 0.f);
        if ((unsigned)iy < NH && (unsigned)ix < NW)
            v = *(const float4*)&x[(size_t)((bb + iy * NW + ix) * NC) + g4];
        half4 h;
        h[0] = (_Float16)v.x; h[1] = (_Float16)v.y;
        h[2] = (_Float16)v.z; h[3] = (_Float16)v.w;
        *(half4*)&s_winh[winh_idx(pos, g4)] = h;
    }
    __syncthreads();

    // ---- phase A: offset conv GEMM from f16 window (all 16 rows real) ----
    const int oc0 = w * 16 + m;     // 0..63
    floatx4 acc0, acc1;
    { const float bv = offb[oc0]; acc0 = (floatx4){bv, bv, bv, bv}; }
    { const float bv = (w == 3 && m < 8) ? offb[64 + m] : 0.0f;
      acc1 = (floatx4){bv, bv, bv, bv}; }

    #pragma unroll
    for (int k = 0; k < NK; ++k) {
        const int ki = k / 3, kj = k - 3 * ki;
        // pixel of row m: (oh + (m>>3), ow0 + (m&7)); window-relative:
        const int pos = (ki + 1 + (m >> 3)) * WC + ((m & 7) + kj + 1);
        #pragma unroll
        for (int s = 0; s < 2; ++s) {
            const half8 af = *(const half8*)&s_winh[winh_idx(pos, s * 32 + kq8)];
            const int kkb = k * 64 + s * 32 + kq8;
            const half8 bf0 = *(const half8*)&offkt[(size_t)oc0 * KTOT + kkb];
            acc0 = __builtin_amdgcn_mfma_f32_16x16x32_f16(af, bf0, acc0, 0, 0, 0);
            if (w == 3) {
                const half8 bf1 = *(const half8*)&offkt[(size_t)(64 + m) * KTOT + kkb];
                acc1 = __builtin_amdgcn_mfma_f32_16x16x32_f16(af, bf1, acc1, 0, 0, 0);
            }
        }
    }
    #pragma unroll
    for (int r = 0; r < 4; ++r)
        s_off[(kq * 4 + r) * NOFF + oc0] = acc0[r];
    if (w == 3 && m < 8) {
        #pragma unroll
        for (int r = 0; r < 4; ++r)
            s_off[(kq * 4 + r) * NOFF + 64 + m] = acc1[r];
    }
    __syncthreads();

    // ---- phase A': coord/weight table, slot = (k*4+g)*16 + p ----
    for (int i = tid; i < 36 * 16; i += 256) {
        const int kg = i >> 4;                  // k*NDG + g
        const int p  = i & 15;                  // pixel 0..15 (all real)
        const int k  = kg >> 2;
        const int ki = k / 3, kj = k - 3 * ki;
        const int ohp = oh + (p >> 3);
        const int owp = ow0 + (p & 7);
        const float offy = s_off[p * NOFF + kg * 2 + 0];
        const float offx = s_off[p * NOFF + kg * 2 + 1];
        float yv = fminf(fmaxf((float)(ohp + ki) + offy, 0.0f), 57.0f);
        float xv = fminf(fmaxf((float)(owp + kj) + offx, 0.0f), 57.0f);
        const float y0f = floorf(yv), x0f = floorf(xv);
        const int y0 = (int)y0f, x0 = (int)x0f;
        const int y1 = min(y0 + 1, 57), x1 = min(x0 + 1, 57);
        const float ly = yv - y0f,       lx = xv - x0f;
        const float hy = (float)y1 - yv, hx = (float)x1 - xv;
        const bool vy0 = (unsigned)(y0 - 1) < NH;
        const bool vy1 = (unsigned)(y1 - 1) < NH;
        const bool vx0 = (unsigned)(x0 - 1) < NW;
        const bool vx1 = (unsigned)(x1 - 1) < NW;
        const float4 wv = make_float4((vy0 && vx0) ? hy * hx : 0.0f,
                                      (vy0 && vx1) ? hy * lx : 0.0f,
                                      (vy1 && vx0) ? ly * hx : 0.0f,
                                      (vy1 && vx1) ? ly * lx : 0.0f);
        const int y0c = min(max(y0 - 1, 0), NH - 1);
        const int y1c = min(max(y1 - 1, 0), NH - 1);
        const int x0c = min(max(x0 - 1, 0), NW - 1);
        const int x1c = min(max(x1 - 1, 0), NW - 1);
        const int ry0 = y0c - oh + 2, ry1 = y1c - oh + 2;
        const int rx0 = x0c - ow0 + 2, rx1 = x1c - ow0 + 2;
        unsigned c0 = 0, c1 = 0, cfv = 0;
        if ((unsigned)ry0 < WR && (unsigned)ry1 < WR &&
            (unsigned)rx0 < WC && (unsigned)rx1 < WC) {
            c0 = (unsigned)(ry0 * WC + rx0) | ((unsigned)(ry0 * WC + rx1) << 16);
            c1 = (unsigned)(ry1 * WC + rx0) | ((unsigned)(ry1 * WC + rx1) << 16);
        } else {                                // rare: coords to s_cwf; pos 0
            cfv = 0x80000000u | ((unsigned)y0c << 18) | ((unsigned)x0c << 12)
                | ((unsigned)y1c << 6) | (unsigned)x1c;
        }
        *(float4*)&s_cww[i * 4] = wv;
        s_cwl[i * 2 + 0] = c0;
        s_cwl[i * 2 + 1] = c1;
        s_cwf[i] = cfv;
    }
    __syncthreads();

    // ---- phase B: branchless window path, packed-f16 blend, rare fixup ----
    floatx4 accB = (floatx4){0.f, 0.f, 0.f, 0.f};
    const int tb = w * 16 + m;                  // table slot (pixel m, group w)
    #pragma unroll
    for (int k = 0; k < NK; ++k) {
        const int sl = k * 64 + tb;
        const float4   cw = *(const float4*)&s_cww[sl * 4];
        const unsigned c0 = s_cwl[sl * 2 + 0];
        const unsigned c1 = s_cwl[sl * 2 + 1];
        const unsigned cf = s_cwf[sl];

        const _Float16* wp = &wkh[(size_t)(k * NF + w * 16 + m) * NC];
        const half8 bf0 = *(const half8*)&wp[kq8];
        const half8 bf1 = *(const half8*)&wp[32 + kq8];

        // always-on window reads (fallback slots read pos 0: benign)
        const int p00 = c0 & 0xFFFF, p01 = c0 >> 16;
        const int p10 = c1 & 0xFFFF, p11 = c1 >> 16;
        const int ca = kq8, cb = 32 + kq8;
        const half8 q00a = *(const half8*)&s_winh[winh_idx(p00, ca)];
        const half8 q01a = *(const half8*)&s_winh[winh_idx(p01, ca)];
        const half8 q10a = *(const half8*)&s_winh[winh_idx(p10, ca)];
        const half8 q11a = *(const half8*)&s_winh[winh_idx(p11, ca)];
        const half8 q00b = *(const half8*)&s_winh[winh_idx(p00, cb)];
        const half8 q01b = *(const half8*)&s_winh[winh_idx(p01, cb)];
        const half8 q10b = *(const half8*)&s_winh[winh_idx(p10, cb)];
        const half8 q11b = *(const half8*)&s_winh[winh_idx(p11, cb)];

        // packed-f16 blend: whole-vector ops -> v_pk_fma_f16 (2 elem/op)
        const _Float16 wx = (_Float16)cw.x, wy = (_Float16)cw.y;
        const _Float16 wz = (_Float16)cw.z, ww2 = (_Float16)cw.w;
        half8 af0 = q00a * wx + q01a * wy + q10a * wz + q11a * ww2;
        half8 af1 = q00b * wx + q01b * wy + q10b * wz + q11b * ww2;

        if (__builtin_expect(cf != 0, 0)) {     // rare fixup: f32 math, overwrite
            const int y0c = (cf >> 18) & 63, x0c = (cf >> 12) & 63;
            const int y1c = (cf >> 6) & 63,  x1c = cf & 63;
            const int i00 = (bb + y0c * NW + x0c) * NC;
            const int i01 = (bb + y0c * NW + x1c) * NC;
            const int i10 = (bb + y1c * NW + x0c) * NC;
            const int i11 = (bb + y1c * NW + x1c) * NC;
            #pragma unroll
            for (int j = 0; j < 8; ++j) {
                float v0 = cw.x * (float)(_Float16)x[i00 + kq8 + j];
                v0 = fmaf(cw.y, (float)(_Float16)x[i01 + kq8 + j], v0);
                v0 = fmaf(cw.z, (float)(_Float16)x[i10 + kq8 + j], v0);
                v0 = fmaf(cw.w, (float)(_Float16)x[i11 + kq8 + j], v0);
                af0[j] = (_Float16)v0;
                float v1 = cw.x * (float)(_Float16)x[i00 + 32 + kq8 + j];
                v1 = fmaf(cw.y, (float)(_Float16)x[i01 + 32 + kq8 + j], v1);
                v1 = fmaf(cw.z, (float)(_Float16)x[i10 + 32 + kq8 + j], v1);
                v1 = fmaf(cw.w, (float)(_Float16)x[i11 + 32 + kq8 + j], v1);
                af1[j] = (_Float16)v1;
            }
        }

        accB = __builtin_amdgcn_mfma_f32_16x16x32_f16(af0, bf0, accB, 0, 0, 0);
        accB = __builtin_amdgcn_mfma_f32_16x16x32_f16(af1, bf1, accB, 0, 0, 0);
    }

    #pragma unroll
    for (int r = 0; r < 4; ++r) {
        const int row = kq * 4 + r;             // all 16 rows are real pixels
        out[(size_t)(bb + (oh + (row >> 3)) * NW + ow0 + (row & 7)) * NF
            + w * 16 + m] = accB[r];
    }
}

extern "C" void kernel_launch(void* const* d_in, const int* in_sizes, int n_in,
                              void* d_out, int out_size, void* d_ws, size_t ws_size,
                              hipStream_t stream) {
    const float* xin  = (const float*)d_in[0];
    const float* offk = (const float*)d_in[1];
    const float* offb = (const float*)d_in[2];
    const float* wk   = (const float*)d_in[3];
    float* outp = (float*)d_out;

    _Float16* offkt = (_Float16*)((char*)d_ws + WS_OFFKT);
    _Float16* wkh   = (_Float16*)((char*)d_ws + WS_WK);

    dcn_prep<<<324, 256, 0, stream>>>(offk, wk, offkt, wkh);
    dcn_main<<<NBLK, 256, 0, stream>>>(xin, offkt, offb, wkh, outp);
}